// Round 1
// 59.603 us; speedup vs baseline: 1.0212x; 1.0212x over previous
//
#include <hip/hip_runtime.h>

// MQCNN quanvolution: inputs (16,3,32,32) f32, weights (16,3,16) f32,
// output (16,16,31,31) f32. One thread per (o, patch); loop over c.
//
// Statevector held as 8 x float2 (packed-fp32 / v_pk_fma_f32 form),
// paired along WIRE 1 (stride 4): v[j] = (s[m], s[m+4]), m = (j&3)|((j&4)<<1).
// With this pairing:
//   RY wire0: componentwise pairs (v[j], v[j+4])            -> packed
//   RY wire1: within-pair: c*v + (-s,s)*v.yx                -> packed (op_sel)
//   RY wire2: componentwise pairs (0,2),(1,3),(4,6),(5,7)   -> packed
//   RY wire3: componentwise pairs (0,1),(2,3),(4,5),(6,7)   -> packed
//   CNOT(0,1) <8,4>: v[4..7] = v[4..7].yx                   (swizzle)
//   CNOT(1,2) <4,2>: swap .y of (0,2),(1,3),(4,6),(5,7)     (v_swap)
//   CNOT(2,3) <2,1>: swap v2<->v3, v6<->v7                  (free rename)
//   CNOT(3,0) <1,8>: swap v1<->v5, v3<->v7                  (free rename)
//
// Exact algebraic reductions (unchanged from previous version):
//  - embed RY(x) + first RY(w) fuse to RY(x+w)
//  - line: z = cos(a0)
//  - ran:  z = cos(w4)cos(a0) - sin(w4)sin(a0)sin(a1)
//  - ring: z = cos(w4)ca1*ca2*ca3 - sin(w4)sa0*sa1
//  - doublering tail prune: drop RY(w13),RY(w14) + 3 tail CNOTs (keep cnot(3,0))
//  - blockring tail prune: drop RY(w9), cnot(0,1), cnot(1,2) in last layer
//  - block-uniform weight sincos staged in LDS (48 half-angle pairs)

#define HPW 961           // 31*31
#define NPATCH 15376      // 16*31*31

typedef float v2 __attribute__((ext_vector_type(2)));

// ---- packed RY sweeps -------------------------------------------------------
__device__ __forceinline__ void ry_pair(v2& A, v2& B, float c, float s) {
    v2 a = A, b = B;
    A = c * a - s * b;
    B = s * a + c * b;
}
__device__ __forceinline__ void ry_w0(v2* v, float c, float s) {
#pragma unroll
    for (int j = 0; j < 4; ++j) ry_pair(v[j], v[j + 4], c, s);
}
__device__ __forceinline__ void ry_w1(v2* v, float c, float s) {
    const v2 sv = {-s, s};
#pragma unroll
    for (int j = 0; j < 8; ++j) {
        v2 a = v[j];
        v2 q = a.yx;
        v[j] = c * a + sv * q;
    }
}
__device__ __forceinline__ void ry_w2(v2* v, float c, float s) {
    ry_pair(v[0], v[2], c, s); ry_pair(v[1], v[3], c, s);
    ry_pair(v[4], v[6], c, s); ry_pair(v[5], v[7], c, s);
}
__device__ __forceinline__ void ry_w3(v2* v, float c, float s) {
    ry_pair(v[0], v[1], c, s); ry_pair(v[2], v[3], c, s);
    ry_pair(v[4], v[5], c, s); ry_pair(v[6], v[7], c, s);
}

// ---- CNOTs ------------------------------------------------------------------
__device__ __forceinline__ void cnot_c0t1(v2* v) {   // cnot_s<8,4>
#pragma unroll
    for (int j = 4; j < 8; ++j) v[j] = v[j].yx;
}
__device__ __forceinline__ void cnot_c1t2(v2* v) {   // cnot_s<4,2>
    float t;
    t = v[0].y; v[0].y = v[2].y; v[2].y = t;
    t = v[1].y; v[1].y = v[3].y; v[3].y = t;
    t = v[4].y; v[4].y = v[6].y; v[6].y = t;
    t = v[5].y; v[5].y = v[7].y; v[7].y = t;
}
__device__ __forceinline__ void cnot_c2t3(v2* v) {   // cnot_s<2,1> (rename)
    v2 t;
    t = v[2]; v[2] = v[3]; v[3] = t;
    t = v[6]; v[6] = v[7]; v[7] = t;
}
__device__ __forceinline__ void cnot_c3t0(v2* v) {   // cnot_s<1,8> (rename)
    v2 t;
    t = v[1]; v[1] = v[5]; v[5] = t;
    t = v[3]; v[3] = v[7]; v[7] = t;
}

// ---- product-state build & measurement -------------------------------------
__device__ __forceinline__ void build16v(v2* v,
        float c0, float s0, float c1, float s1,
        float c2, float s2, float c3, float s3) {
    const v2 M0 = {c0 * c1, c0 * s1};
    const v2 M1 = {s0 * c1, s0 * s1};
    const float n0 = c2 * c3, n1 = c2 * s3, n2 = s2 * c3, n3 = s2 * s3;
    v[0] = n0 * M0; v[1] = n1 * M0; v[2] = n2 * M0; v[3] = n3 * M0;
    v[4] = n0 * M1; v[5] = n1 * M1; v[6] = n2 * M1; v[7] = n3 * M1;
}

__device__ __forceinline__ float expz0v(const v2* v) {
    v2 e = v[0] * v[0];
    e += v[1] * v[1]; e += v[2] * v[2]; e += v[3] * v[3];
    e -= v[4] * v[4]; e -= v[5] * v[5]; e -= v[6] * v[6]; e -= v[7] * v[7];
    return e.x + e.y;
}

__global__ __launch_bounds__(256) void quanv_kernel(const float* __restrict__ in,
                                                    const float* __restrict__ wts,
                                                    float* __restrict__ out) {
    __shared__ float2 wcs[48];            // half-angle {cos, sin} of weights
    const int o = blockIdx.y;             // block-uniform
    const int t = threadIdx.x;
    const float* W = wts + o * 48;        // uniform -> s_load

    if (t < 48) {
        float sn, cs;
        __sincosf(0.5f * W[t], &sn, &cs);
        wcs[t] = make_float2(cs, sn);
    }
    __syncthreads();

    const int pidx = blockIdx.x * 256 + t;
    if (pidx >= NPATCH) return;
    const int b   = pidx / HPW;
    const int rem = pidx - b * HPW;
    const int h   = rem / 31;
    const int w   = rem - h * 31;
    const int circ = o % 5;               // uniform per block

    const float* p0 = in + ((b * 3) * 32 + h) * 32 + w;
    float acc = 0.0f;

    switch (circ) {
    case 0: { // ran: z = cos(w4)cos(a0) - sin(w4)sin(a0)sin(a1)
#pragma unroll
        for (int c = 0; c < 3; ++c) {
            const float* p  = p0 + c * 1024;
            const float* wc = W + c * 16;
            const float2 h4 = wcs[c * 16 + 4];
            const float cf = fmaf(-2.0f * h4.y, h4.y, 1.0f);  // cos w4
            const float sf = 2.0f * h4.x * h4.y;              // sin w4
            float sa0, ca0; __sincosf(p[0] + wc[0], &sa0, &ca0);
            const float sa1 = __sinf(p[1] + wc[1]);
            acc += cf * ca0 - sf * sa0 * sa1;
        }
    } break;
    case 1: { // line: z = cos(a0)
#pragma unroll
        for (int c = 0; c < 3; ++c)
            acc += __cosf(p0[c * 1024] + W[c * 16]);
    } break;
    case 2: { // ring: z = cos(w4)ca1*ca2*ca3 - sin(w4)sa0*sa1
#pragma unroll
        for (int c = 0; c < 3; ++c) {
            const float* p  = p0 + c * 1024;
            const float* wc = W + c * 16;
            const float2 h4 = wcs[c * 16 + 4];
            const float cf = fmaf(-2.0f * h4.y, h4.y, 1.0f);
            const float sf = 2.0f * h4.x * h4.y;
            const float sa0 = __sinf(p[0] + wc[0]);
            float sa1, ca1; __sincosf(p[1] + wc[1], &sa1, &ca1);
            const float ca2 = __cosf(p[32] + wc[2]);
            const float ca3 = __cosf(p[33] + wc[3]);
            acc += cf * ca1 * ca2 * ca3 - sf * sa0 * sa1;
        }
    } break;
    case 3: { // doublering (tail-pruned): 10 weight RYs per c, packed fp32
#pragma unroll
        for (int c = 0; c < 3; ++c) {
            const float* p  = p0 + c * 1024;
            const float* wc = W + c * 16;
            const float2* g = wcs + c * 16;
            float c0,s0,c1,s1,c2,s2,c3,s3;
            __sincosf(0.5f * (p[0]  + wc[0]), &s0, &c0);
            __sincosf(0.5f * (p[1]  + wc[1]), &s1, &c1);
            __sincosf(0.5f * (p[32] + wc[2]), &s2, &c2);
            __sincosf(0.5f * (p[33] + wc[3]), &s3, &c3);
            v2 v[8]; build16v(v, c0,s0,c1,s1,c2,s2,c3,s3);
            // L0: ring (0,1),(1,2),(2,3),(3,0)
            cnot_c0t1(v); cnot_c1t2(v); cnot_c2t3(v); cnot_c3t0(v);
            ry_w0(v, g[4].x, g[4].y); ry_w1(v, g[5].x, g[5].y);
            ry_w2(v, g[6].x, g[6].y); ry_w3(v, g[7].x, g[7].y);
            // reversed ring
            cnot_c3t0(v); cnot_c2t3(v); cnot_c1t2(v); cnot_c0t1(v);
            // L1
            ry_w0(v, g[8].x, g[8].y);  ry_w1(v, g[9].x, g[9].y);
            ry_w2(v, g[10].x, g[10].y); ry_w3(v, g[11].x, g[11].y);
            cnot_c0t1(v); cnot_c1t2(v); cnot_c2t3(v); cnot_c3t0(v);
            ry_w0(v, g[12].x, g[12].y); ry_w3(v, g[15].x, g[15].y); // w13,w14 pruned
            cnot_c3t0(v);                                            // only cnot(3,0) survives
            acc += expz0v(v);
        }
    } break;
    default: { // blockring (tail-pruned): 7 weight RYs per c, packed fp32
#pragma unroll
        for (int c = 0; c < 3; ++c) {
            const float* p  = p0 + c * 1024;
            const float* wc = W + c * 16;
            const float2* g = wcs + c * 16;
            float c0,s0,c1,s1,c2,s2,c3,s3;
            __sincosf(0.5f * (p[0]  + wc[0]), &s0, &c0);
            __sincosf(0.5f * (p[1]  + wc[1]), &s1, &c1);
            __sincosf(0.5f * (p[32] + wc[2]), &s2, &c2);
            __sincosf(0.5f * (p[33] + wc[3]), &s3, &c3);
            v2 v[8]; build16v(v, c0,s0,c1,s1,c2,s2,c3,s3);
            // L0 cnots: (0,1),(2,3),(1,2),(3,0)
            cnot_c0t1(v); cnot_c2t3(v); cnot_c1t2(v); cnot_c3t0(v);
            ry_w0(v, g[4].x, g[4].y); ry_w1(v, g[5].x, g[5].y);
            ry_w2(v, g[6].x, g[6].y); ry_w3(v, g[7].x, g[7].y);
            // L1 cnots
            cnot_c0t1(v); cnot_c2t3(v); cnot_c1t2(v); cnot_c3t0(v);
            // L2: RY(w9,wire1) pruned; cnot(0,1),(1,2) pruned
            ry_w0(v, g[8].x, g[8].y); ry_w2(v, g[10].x, g[10].y);
            ry_w3(v, g[11].x, g[11].y);
            cnot_c2t3(v); cnot_c3t0(v);
            acc += expz0v(v);
        }
    } break;
    }

    out[((b * 16 + o) * 31 + h) * 31 + w] = acc;
}

extern "C" void kernel_launch(void* const* d_in, const int* in_sizes, int n_in,
                              void* d_out, int out_size, void* d_ws, size_t ws_size,
                              hipStream_t stream) {
    const float* in  = (const float*)d_in[0];
    const float* wts = (const float*)d_in[1];
    float* out = (float*)d_out;
    dim3 grid((NPATCH + 255) / 256, 16);
    quanv_kernel<<<grid, 256, 0, stream>>>(in, wts, out);
}